// Round 2
// baseline (495.003 us; speedup 1.0000x reference)
//
#include <hip/hip_runtime.h>
#include <math.h>

#define NPTS 262144
#define PLANE_ELEMS (16777216u)   // 256*256*256

// ---------------------------------------------------------------------------
// Transpose (C, H*W) -> (H*W, C) for all 3 planes. 32x32 LDS tiles.
// blockDim (32,8); grid (65536/32, 256/32, 3)
// ---------------------------------------------------------------------------
__global__ __launch_bounds__(256) void PREFFFT_trans_k(
    const float* __restrict__ Pu, const float* __restrict__ Pv,
    const float* __restrict__ Pw, float* __restrict__ dstws) {
  __shared__ float tile[32][33];
  const float* src = blockIdx.z == 0 ? Pu : (blockIdx.z == 1 ? Pv : Pw);
  float* dst = dstws + (size_t)blockIdx.z * PLANE_ELEMS;
  unsigned hw0 = blockIdx.x * 32u;
  unsigned c0  = blockIdx.y * 32u;
  unsigned x = threadIdx.x;   // 0..31
  unsigned yb = threadIdx.y;  // 0..7
#pragma unroll
  for (int i = 0; i < 4; ++i) {
    unsigned c = c0 + yb + i * 8u;
    tile[yb + i * 8u][x] = src[(size_t)c * 65536u + hw0 + x];
  }
  __syncthreads();
#pragma unroll
  for (int i = 0; i < 4; ++i) {
    unsigned hw = hw0 + yb + i * 8u;
    dst[(size_t)hw * 256u + c0 + x] = tile[x][yb + i * 8u];
  }
}

// ---------------------------------------------------------------------------
// Main kernel: 32 threads per point. Thread t owns channels [t*8, t*8+8)
// == (ch2=t, r=0..7). t<16 -> real (cos), t>=16 -> imag (sin).
// TRANSPOSED=1: planes are (H, W, C) in ws. TRANSPOSED=0: original (C, H, W).
// ---------------------------------------------------------------------------
template <int TRANSPOSED>
__global__ __launch_bounds__(256) void PREFFFT_samp_k(
    const float* __restrict__ inputs, const float* __restrict__ Tu,
    const float* __restrict__ Tv, const float* __restrict__ Tw,
    float* __restrict__ out) {
  int gtid = blockIdx.x * 256 + threadIdx.x;
  int n = gtid >> 5;
  int t = threadIdx.x & 31;
  const bool is_re = t < 16;

  float c0 = inputs[n * 3 + 0];
  float c1 = inputs[n * 3 + 1];
  float c2 = inputs[n * 3 + 2];

  const float* PL[3] = {Tu, Tv, Tw};
  float GX[3] = {c1, c0, c0};
  float GY[3] = {c2, c2, c1};
  float AX[3] = {c0, c1, c2};

  float acc = 0.f;

#pragma unroll
  for (int pl = 0; pl < 3; ++pl) {
    const float* __restrict__ P = PL[pl];
    float ix = (GX[pl] + 1.f) * 0.5f * 255.f;
    float iy = (GY[pl] + 1.f) * 0.5f * 255.f;
    float x0f = floorf(ix), y0f = floorf(iy);
    float wx = ix - x0f, wy = iy - y0f;
    int x0 = (int)x0f; x0 = x0 < 0 ? 0 : (x0 > 255 ? 255 : x0);
    int y0 = (int)y0f; y0 = y0 < 0 ? 0 : (y0 > 255 ? 255 : y0);
    int x1 = x0 + 1 > 255 ? 255 : x0 + 1;
    int y1 = y0 + 1 > 255 ? 255 : y0 + 1;
    float w00 = (1.f - wx) * (1.f - wy);
    float w01 = wx * (1.f - wy);
    float w10 = (1.f - wx) * wy;
    float w11 = wx * wy;

    float b[8] = {0.f, 0.f, 0.f, 0.f, 0.f, 0.f, 0.f, 0.f};

    if (TRANSPOSED) {
      int o00 = (y0 * 256 + x0) * 256 + t * 8;
      int o01 = (y0 * 256 + x1) * 256 + t * 8;
      int o10 = (y1 * 256 + x0) * 256 + t * 8;
      int o11 = (y1 * 256 + x1) * 256 + t * 8;
      {
        const float4* q = (const float4*)(P + o00);
        float4 a = q[0], a2 = q[1];
        b[0] += w00 * a.x;  b[1] += w00 * a.y;  b[2] += w00 * a.z;  b[3] += w00 * a.w;
        b[4] += w00 * a2.x; b[5] += w00 * a2.y; b[6] += w00 * a2.z; b[7] += w00 * a2.w;
      }
      {
        const float4* q = (const float4*)(P + o01);
        float4 a = q[0], a2 = q[1];
        b[0] += w01 * a.x;  b[1] += w01 * a.y;  b[2] += w01 * a.z;  b[3] += w01 * a.w;
        b[4] += w01 * a2.x; b[5] += w01 * a2.y; b[6] += w01 * a2.z; b[7] += w01 * a2.w;
      }
      {
        const float4* q = (const float4*)(P + o10);
        float4 a = q[0], a2 = q[1];
        b[0] += w10 * a.x;  b[1] += w10 * a.y;  b[2] += w10 * a.z;  b[3] += w10 * a.w;
        b[4] += w10 * a2.x; b[5] += w10 * a2.y; b[6] += w10 * a2.z; b[7] += w10 * a2.w;
      }
      {
        const float4* q = (const float4*)(P + o11);
        float4 a = q[0], a2 = q[1];
        b[0] += w11 * a.x;  b[1] += w11 * a.y;  b[2] += w11 * a.z;  b[3] += w11 * a.w;
        b[4] += w11 * a2.x; b[5] += w11 * a2.y; b[6] += w11 * a2.z; b[7] += w11 * a2.w;
      }
    } else {
      // Fallback: original (C,H,W) layout, strided scalar loads (slow, correct)
      int i00 = y0 * 256 + x0, i01 = y0 * 256 + x1;
      int i10 = y1 * 256 + x0, i11 = y1 * 256 + x1;
#pragma unroll
      for (int j = 0; j < 8; ++j) {
        const float* base = P + (size_t)(t * 8 + j) * 65536u;
        b[j] = w00 * base[i00] + w01 * base[i01] + w10 * base[i10] + w11 * base[i11];
      }
    }

    // Fourier contraction: theta_r = 2*pi*cs*coef_r, coef = [0,1,2,4,...,64]/256
    float cs = (AX[pl] + 1.f) * 0.5f * 255.f;
    float theta1 = 6.283185307179586f * cs * (1.f / 256.f);
    float partial = is_re ? b[0] : 0.f;  // r=0: cos=1, sin=0
#pragma unroll
    for (int r = 1; r < 8; ++r) {
      float th = theta1 * (float)(1 << (r - 1));
      float s, c;
      __sincosf(th, &s, &c);
      partial += b[r] * (is_re ? c : s);
    }
    float other = __shfl_xor(partial, 16);
    acc += partial - other;  // real lanes: re - im
  }

  if (is_re) out[n * 16 + t] = acc;
}

extern "C" void kernel_launch(void* const* d_in, const int* in_sizes, int n_in,
                              void* d_out, int out_size, void* d_ws, size_t ws_size,
                              hipStream_t stream) {
  const float* inputs = (const float*)d_in[0];
  const float* Pu = (const float*)d_in[1];
  const float* Pv = (const float*)d_in[2];
  const float* Pw = (const float*)d_in[3];
  float* out = (float*)d_out;

  size_t need = (size_t)3 * PLANE_ELEMS * sizeof(float);
  if (ws_size >= need) {
    float* T = (float*)d_ws;
    dim3 tb(32, 8), tg(65536 / 32, 256 / 32, 3);
    PREFFFT_trans_k<<<tg, tb, 0, stream>>>(Pu, Pv, Pw, T);
    PREFFFT_samp_k<1><<<NPTS / 8, 256, 0, stream>>>(
        inputs, T, T + PLANE_ELEMS, T + 2 * PLANE_ELEMS, out);
  } else {
    PREFFFT_samp_k<0><<<NPTS / 8, 256, 0, stream>>>(inputs, Pu, Pv, Pw, out);
  }
}

// Round 3
// 269.002 us; speedup vs baseline: 1.8401x; 1.8401x over previous
//
#include <hip/hip_runtime.h>
#include <hip/hip_fp16.h>
#include <math.h>

#define NPTS 262144
#define PLANE_ELEMS (16777216u)   // 256*256*256

typedef __attribute__((ext_vector_type(4))) float f4;

// ---------------------------------------------------------------------------
// Transpose + convert: (C, H*W) fp32 -> (H*W, C) fp16 for all 3 planes.
// blockDim (32,8); grid (65536/32, 256/64, 3). 64-channel-wide tiles so the
// fp16 writes are one __half2 (4B) per lane, 128B contiguous per row.
// ---------------------------------------------------------------------------
__global__ __launch_bounds__(256) void PREFFFT_trans_k(
    const float* __restrict__ Pu, const float* __restrict__ Pv,
    const float* __restrict__ Pw, __half* __restrict__ dstws) {
  __shared__ float tile[64][33];
  const float* src = blockIdx.z == 0 ? Pu : (blockIdx.z == 1 ? Pv : Pw);
  __half* dst = dstws + (size_t)blockIdx.z * PLANE_ELEMS;
  unsigned hw0 = blockIdx.x * 32u;
  unsigned c0  = blockIdx.y * 64u;
  unsigned x = threadIdx.x;   // 0..31
  unsigned yb = threadIdx.y;  // 0..7
#pragma unroll
  for (int i = 0; i < 8; ++i) {
    unsigned cl = yb + i * 8u;
    tile[cl][x] = src[(size_t)(c0 + cl) * 65536u + hw0 + x];
  }
  __syncthreads();
#pragma unroll
  for (int i = 0; i < 4; ++i) {
    unsigned hwl = yb + i * 8u;
    float lo = tile[2u * x][hwl];
    float hi = tile[2u * x + 1u][hwl];
    *(__half2*)(dst + (size_t)(hw0 + hwl) * 256u + c0 + 2u * x) =
        __floats2half2_rn(lo, hi);
  }
}

// ---------------------------------------------------------------------------
// Main kernel: 32 threads per point. Thread t owns channels [t*8, t*8+8)
// == (ch2=t, r=0..7). t<16 -> real (cos), t>=16 -> imag (sin).
// TRANSPOSED=1: planes are (H, W, C) fp16 in ws (one 16B load per corner).
// TRANSPOSED=0: original (C, H, W) fp32 (slow, correct fallback).
// ---------------------------------------------------------------------------
template <int TRANSPOSED>
__global__ __launch_bounds__(256) void PREFFFT_samp_k(
    const float* __restrict__ inputs, const void* __restrict__ Tu,
    const void* __restrict__ Tv, const void* __restrict__ Tw,
    float* __restrict__ out) {
  int gtid = blockIdx.x * 256 + threadIdx.x;
  int n = gtid >> 5;
  int t = threadIdx.x & 31;
  const bool is_re = t < 16;

  float c0 = inputs[n * 3 + 0];
  float c1 = inputs[n * 3 + 1];
  float c2 = inputs[n * 3 + 2];

  const void* PL[3] = {Tu, Tv, Tw};
  float GX[3] = {c1, c0, c0};
  float GY[3] = {c2, c2, c1};
  float AX[3] = {c0, c1, c2};

  float acc = 0.f;

#pragma unroll
  for (int pl = 0; pl < 3; ++pl) {
    float ix = (GX[pl] + 1.f) * 0.5f * 255.f;
    float iy = (GY[pl] + 1.f) * 0.5f * 255.f;
    float x0f = floorf(ix), y0f = floorf(iy);
    float wx = ix - x0f, wy = iy - y0f;
    int x0 = (int)x0f; x0 = x0 < 0 ? 0 : (x0 > 255 ? 255 : x0);
    int y0 = (int)y0f; y0 = y0 < 0 ? 0 : (y0 > 255 ? 255 : y0);
    int x1 = x0 + 1 > 255 ? 255 : x0 + 1;
    int y1 = y0 + 1 > 255 ? 255 : y0 + 1;
    float w00 = (1.f - wx) * (1.f - wy);
    float w01 = wx * (1.f - wy);
    float w10 = (1.f - wx) * wy;
    float w11 = wx * wy;

    float b[8] = {0.f, 0.f, 0.f, 0.f, 0.f, 0.f, 0.f, 0.f};

    if (TRANSPOSED) {
      const __half* __restrict__ P = (const __half*)PL[pl];
      int o00 = (y0 * 256 + x0) * 256 + t * 8;
      int o01 = (y0 * 256 + x1) * 256 + t * 8;
      int o10 = (y1 * 256 + x0) * 256 + t * 8;
      int o11 = (y1 * 256 + x1) * 256 + t * 8;
      f4 r00 = *(const f4*)(P + o00);
      f4 r01 = *(const f4*)(P + o01);
      f4 r10 = *(const f4*)(P + o10);
      f4 r11 = *(const f4*)(P + o11);
      const __half2* h;
#pragma unroll
      for (int q = 0; q < 4; ++q) {
        h = (const __half2*)&r00;
        float2 v = __half22float2(h[q]);
        b[2 * q] += w00 * v.x; b[2 * q + 1] += w00 * v.y;
      }
#pragma unroll
      for (int q = 0; q < 4; ++q) {
        h = (const __half2*)&r01;
        float2 v = __half22float2(h[q]);
        b[2 * q] += w01 * v.x; b[2 * q + 1] += w01 * v.y;
      }
#pragma unroll
      for (int q = 0; q < 4; ++q) {
        h = (const __half2*)&r10;
        float2 v = __half22float2(h[q]);
        b[2 * q] += w10 * v.x; b[2 * q + 1] += w10 * v.y;
      }
#pragma unroll
      for (int q = 0; q < 4; ++q) {
        h = (const __half2*)&r11;
        float2 v = __half22float2(h[q]);
        b[2 * q] += w11 * v.x; b[2 * q + 1] += w11 * v.y;
      }
    } else {
      // Fallback: original (C,H,W) fp32 layout, strided scalar loads
      const float* __restrict__ P = (const float*)PL[pl];
      int i00 = y0 * 256 + x0, i01 = y0 * 256 + x1;
      int i10 = y1 * 256 + x0, i11 = y1 * 256 + x1;
#pragma unroll
      for (int j = 0; j < 8; ++j) {
        const float* base = P + (size_t)(t * 8 + j) * 65536u;
        b[j] = w00 * base[i00] + w01 * base[i01] + w10 * base[i10] + w11 * base[i11];
      }
    }

    // Fourier contraction: theta_r = 2*pi*cs*coef_r, coef = [0,1,2,4,...,64]/256
    float cs = (AX[pl] + 1.f) * 0.5f * 255.f;
    float theta1 = 6.283185307179586f * cs * (1.f / 256.f);
    float partial = is_re ? b[0] : 0.f;  // r=0: cos=1, sin=0
#pragma unroll
    for (int r = 1; r < 8; ++r) {
      float th = theta1 * (float)(1 << (r - 1));
      float s, c;
      __sincosf(th, &s, &c);
      partial += b[r] * (is_re ? c : s);
    }
    float other = __shfl_xor(partial, 16);
    acc += partial - other;  // real lanes: re - im
  }

  if (is_re) out[n * 16 + t] = acc;
}

extern "C" void kernel_launch(void* const* d_in, const int* in_sizes, int n_in,
                              void* d_out, int out_size, void* d_ws, size_t ws_size,
                              hipStream_t stream) {
  const float* inputs = (const float*)d_in[0];
  const float* Pu = (const float*)d_in[1];
  const float* Pv = (const float*)d_in[2];
  const float* Pw = (const float*)d_in[3];
  float* out = (float*)d_out;

  size_t need = (size_t)3 * PLANE_ELEMS * sizeof(__half);
  if (ws_size >= need) {
    __half* T = (__half*)d_ws;
    dim3 tb(32, 8), tg(65536 / 32, 256 / 64, 3);
    PREFFFT_trans_k<<<tg, tb, 0, stream>>>(Pu, Pv, Pw, T);
    PREFFFT_samp_k<1><<<NPTS / 8, 256, 0, stream>>>(
        inputs, T, T + PLANE_ELEMS, T + 2 * PLANE_ELEMS, out);
  } else {
    PREFFFT_samp_k<0><<<NPTS / 8, 256, 0, stream>>>(inputs, Pu, Pv, Pw, out);
  }
}

// Round 4
// 257.647 us; speedup vs baseline: 1.9212x; 1.0441x over previous
//
#include <hip/hip_runtime.h>
#include <hip/hip_fp16.h>
#include <math.h>

#define NPTS 262144
#define PLANE_ELEMS 16777216u   // 256*256*256

typedef __attribute__((ext_vector_type(4))) float f4;

// ws layout (bytes):
//   [0, 96 MB)                 : fp16 transposed planes (3 x 32 MB)
//   [96 MB, +12.58 MB)         : sortedC float4[3][NPTS] (c0,c1,c2,bits(n))
//   [.., +50.33 MB)            : partial float[3][NPTS][16]
//   [.., +0.75 MB)             : hist unsigned[3][65536]
#define OFF_SORTED   (3ull * PLANE_ELEMS * 2ull)                  // 100663296
#define OFF_PARTIAL  (OFF_SORTED + (size_t)3 * NPTS * 16)         // +12582912
#define OFF_HIST     (OFF_PARTIAL + (size_t)3 * NPTS * 16 * 4)    // +50331648
#define WS_NEED      (OFF_HIST + (size_t)3 * 65536 * 4)

__device__ __forceinline__ void plane_xy(int p, float c0, float c1, float c2,
                                         float& gx, float& gy, float& ax) {
  if (p == 0)      { gx = c1; gy = c2; ax = c0; }
  else if (p == 1) { gx = c0; gy = c2; ax = c1; }
  else             { gx = c0; gy = c1; ax = c2; }
}

__device__ __forceinline__ int cell_of(float g) {
  float i = (g + 1.f) * 0.5f * 255.f;
  int x0 = (int)floorf(i);
  return x0 < 0 ? 0 : (x0 > 255 ? 255 : x0);
}

// ---------------------------------------------------------------------------
// Transpose + convert: (C, H*W) fp32 -> (H*W, C) fp16 for all 3 planes.
// ---------------------------------------------------------------------------
__global__ __launch_bounds__(256) void PREFFFT_trans_k(
    const float* __restrict__ Pu, const float* __restrict__ Pv,
    const float* __restrict__ Pw, __half* __restrict__ dstws) {
  __shared__ float tile[64][33];
  const float* src = blockIdx.z == 0 ? Pu : (blockIdx.z == 1 ? Pv : Pw);
  __half* dst = dstws + (size_t)blockIdx.z * PLANE_ELEMS;
  unsigned hw0 = blockIdx.x * 32u;
  unsigned c0  = blockIdx.y * 64u;
  unsigned x = threadIdx.x;   // 0..31
  unsigned yb = threadIdx.y;  // 0..7
#pragma unroll
  for (int i = 0; i < 8; ++i) {
    unsigned cl = yb + i * 8u;
    tile[cl][x] = src[(size_t)(c0 + cl) * 65536u + hw0 + x];
  }
  __syncthreads();
#pragma unroll
  for (int i = 0; i < 4; ++i) {
    unsigned hwl = yb + i * 8u;
    float lo = tile[2u * x][hwl];
    float hi = tile[2u * x + 1u][hwl];
    *(__half2*)(dst + (size_t)(hw0 + hwl) * 256u + c0 + 2u * x) =
        __floats2half2_rn(lo, hi);
  }
}

// ---------------------------------------------------------------------------
// Sort pass 1: histogram of 16-bit plane-cell keys, 3 planes.
// ---------------------------------------------------------------------------
__global__ __launch_bounds__(256) void PREFFFT_hist_k(
    const float* __restrict__ inputs, unsigned* __restrict__ hist) {
  int n = blockIdx.x * 256 + threadIdx.x;
  if (n >= NPTS) return;
  float c0 = inputs[n * 3 + 0];
  float c1 = inputs[n * 3 + 1];
  float c2 = inputs[n * 3 + 2];
#pragma unroll
  for (int p = 0; p < 3; ++p) {
    float gx, gy, ax;
    plane_xy(p, c0, c1, c2, gx, gy, ax);
    int key = (cell_of(gy) << 8) | cell_of(gx);
    atomicAdd(&hist[p * 65536 + key], 1u);
  }
}

// ---------------------------------------------------------------------------
// Sort pass 2: exclusive scan of 65536 bins; one block per plane.
// ---------------------------------------------------------------------------
__global__ __launch_bounds__(1024) void PREFFFT_scan_k(unsigned* __restrict__ hist) {
  __shared__ unsigned part[1024];
  unsigned* h = hist + (size_t)blockIdx.x * 65536;
  int t = threadIdx.x;
  unsigned s = 0;
#pragma unroll 8
  for (int i = 0; i < 64; ++i) s += h[t * 64 + i];
  part[t] = s;
  __syncthreads();
  for (int off = 1; off < 1024; off <<= 1) {
    unsigned v = (t >= off) ? part[t - off] : 0u;
    __syncthreads();
    part[t] += v;
    __syncthreads();
  }
  unsigned run = (t == 0) ? 0u : part[t - 1];
#pragma unroll 8
  for (int i = 0; i < 64; ++i) {
    unsigned c = h[t * 64 + i];
    h[t * 64 + i] = run;
    run += c;
  }
}

// ---------------------------------------------------------------------------
// Sort pass 3: scatter (c0,c1,c2,n) into cell-sorted order per plane.
// ---------------------------------------------------------------------------
__global__ __launch_bounds__(256) void PREFFFT_scat_k(
    const float* __restrict__ inputs, unsigned* __restrict__ hist,
    float4* __restrict__ sortedC) {
  int n = blockIdx.x * 256 + threadIdx.x;
  if (n >= NPTS) return;
  float c0 = inputs[n * 3 + 0];
  float c1 = inputs[n * 3 + 1];
  float c2 = inputs[n * 3 + 2];
#pragma unroll
  for (int p = 0; p < 3; ++p) {
    float gx, gy, ax;
    plane_xy(p, c0, c1, c2, gx, gy, ax);
    int key = (cell_of(gy) << 8) | cell_of(gx);
    unsigned pos = atomicAdd(&hist[p * 65536 + key], 1u);
    sortedC[(size_t)p * NPTS + pos] =
        make_float4(c0, c1, c2, __uint_as_float((unsigned)n));
  }
}

// ---------------------------------------------------------------------------
// Sample pass: one plane per blockIdx.y, cell-sorted points; 32 thr/point.
// Thread t owns channels [t*8, t*8+8); t<16 real (cos), t>=16 imag (sin).
// Writes re-im partials (full 64B line per point) -> partial[p][n][16].
// ---------------------------------------------------------------------------
__global__ __launch_bounds__(256) void PREFFFT_samp_k(
    const float4* __restrict__ sortedC, const __half* __restrict__ T,
    float* __restrict__ partial) {
  int p = blockIdx.y;
  // XCD-contiguous chunking within each plane (32768 blocks, 8 XCDs)
  int bx = blockIdx.x;
  int lbx = (bx & 7) * 4096 + (bx >> 3);
  int slot = lbx * 8 + ((int)threadIdx.x >> 5);
  int t = threadIdx.x & 31;
  const bool is_re = t < 16;

  float4 sc = sortedC[(size_t)p * NPTS + slot];
  unsigned n = __float_as_uint(sc.w);
  float gx, gy, ax;
  plane_xy(p, sc.x, sc.y, sc.z, gx, gy, ax);

  float ix = (gx + 1.f) * 0.5f * 255.f;
  float iy = (gy + 1.f) * 0.5f * 255.f;
  float x0f = floorf(ix), y0f = floorf(iy);
  float wx = ix - x0f, wy = iy - y0f;
  int x0 = (int)x0f; x0 = x0 < 0 ? 0 : (x0 > 255 ? 255 : x0);
  int y0 = (int)y0f; y0 = y0 < 0 ? 0 : (y0 > 255 ? 255 : y0);
  int x1 = x0 + 1 > 255 ? 255 : x0 + 1;
  int y1 = y0 + 1 > 255 ? 255 : y0 + 1;
  float w00 = (1.f - wx) * (1.f - wy);
  float w01 = wx * (1.f - wy);
  float w10 = (1.f - wx) * wy;
  float w11 = wx * wy;

  const __half* __restrict__ P = T + (size_t)p * PLANE_ELEMS;
  int o00 = (y0 * 256 + x0) * 256 + t * 8;
  int o01 = (y0 * 256 + x1) * 256 + t * 8;
  int o10 = (y1 * 256 + x0) * 256 + t * 8;
  int o11 = (y1 * 256 + x1) * 256 + t * 8;
  f4 r00 = *(const f4*)(P + o00);
  f4 r01 = *(const f4*)(P + o01);
  f4 r10 = *(const f4*)(P + o10);
  f4 r11 = *(const f4*)(P + o11);

  float b[8];
#pragma unroll
  for (int q = 0; q < 4; ++q) {
    float2 v00 = __half22float2(((const __half2*)&r00)[q]);
    float2 v01 = __half22float2(((const __half2*)&r01)[q]);
    float2 v10 = __half22float2(((const __half2*)&r10)[q]);
    float2 v11 = __half22float2(((const __half2*)&r11)[q]);
    b[2 * q]     = w00 * v00.x + w01 * v01.x + w10 * v10.x + w11 * v11.x;
    b[2 * q + 1] = w00 * v00.y + w01 * v01.y + w10 * v10.y + w11 * v11.y;
  }

  // Fourier: theta_r = theta1 * 2^(r-1), r=1..7; r=0 term is cos=1/sin=0.
  float cs = (ax + 1.f) * 0.5f * 255.f;
  float theta1 = 6.283185307179586f * cs * (1.f / 256.f);
  float s, c;
  __sincosf(theta1, &s, &c);
  float acc = is_re ? b[0] : 0.f;
#pragma unroll
  for (int r = 1; r < 7; ++r) {
    acc += b[r] * (is_re ? c : s);
    // double angle: c' = 2c^2 - 1, s' = 2sc
    float c2 = c + c;
    float cn = c2 * c - 1.f;
    s = c2 * s;
    c = cn;
  }
  acc += b[7] * (is_re ? c : s);

  float other = __shfl_xor(acc, 16);
  float val = acc - other;  // re lanes: re - im
  if (is_re) partial[((size_t)p * NPTS + n) * 16 + t] = val;
}

// ---------------------------------------------------------------------------
// Reduce: out = partial[0] + partial[1] + partial[2], float4-vectorized.
// ---------------------------------------------------------------------------
__global__ __launch_bounds__(256) void PREFFFT_red_k(
    const f4* __restrict__ part, f4* __restrict__ out) {
  int i = blockIdx.x * 256 + threadIdx.x;  // < 1048576
  f4 a = part[i];
  f4 b = part[1048576 + i];
  f4 c = part[2 * 1048576 + i];
  out[i] = a + b + c;
}

// ---------------------------------------------------------------------------
// Fallback (ws too small): original (C,H,W) fp32 direct, slow but correct.
// ---------------------------------------------------------------------------
__global__ __launch_bounds__(256) void PREFFFT_fallback_k(
    const float* __restrict__ inputs, const float* __restrict__ Tu,
    const float* __restrict__ Tv, const float* __restrict__ Tw,
    float* __restrict__ out) {
  int gtid = blockIdx.x * 256 + threadIdx.x;
  int n = gtid >> 5;
  int t = threadIdx.x & 31;
  const bool is_re = t < 16;
  float c0 = inputs[n * 3 + 0], c1 = inputs[n * 3 + 1], c2 = inputs[n * 3 + 2];
  const float* PL[3] = {Tu, Tv, Tw};
  float acc = 0.f;
#pragma unroll
  for (int p = 0; p < 3; ++p) {
    float gx, gy, ax;
    plane_xy(p, c0, c1, c2, gx, gy, ax);
    float ix = (gx + 1.f) * 0.5f * 255.f;
    float iy = (gy + 1.f) * 0.5f * 255.f;
    float x0f = floorf(ix), y0f = floorf(iy);
    float wx = ix - x0f, wy = iy - y0f;
    int x0 = (int)x0f; x0 = x0 < 0 ? 0 : (x0 > 255 ? 255 : x0);
    int y0 = (int)y0f; y0 = y0 < 0 ? 0 : (y0 > 255 ? 255 : y0);
    int x1 = x0 + 1 > 255 ? 255 : x0 + 1;
    int y1 = y0 + 1 > 255 ? 255 : y0 + 1;
    float w00 = (1.f - wx) * (1.f - wy), w01 = wx * (1.f - wy);
    float w10 = (1.f - wx) * wy, w11 = wx * wy;
    int i00 = y0 * 256 + x0, i01 = y0 * 256 + x1;
    int i10 = y1 * 256 + x0, i11 = y1 * 256 + x1;
    float b[8];
#pragma unroll
    for (int j = 0; j < 8; ++j) {
      const float* base = PL[p] + (size_t)(t * 8 + j) * 65536u;
      b[j] = w00 * base[i00] + w01 * base[i01] + w10 * base[i10] + w11 * base[i11];
    }
    float cs = (ax + 1.f) * 0.5f * 255.f;
    float theta1 = 6.283185307179586f * cs * (1.f / 256.f);
    float partial = is_re ? b[0] : 0.f;
#pragma unroll
    for (int r = 1; r < 8; ++r) {
      float th = theta1 * (float)(1 << (r - 1));
      float s, c;
      __sincosf(th, &s, &c);
      partial += b[r] * (is_re ? c : s);
    }
    float other = __shfl_xor(partial, 16);
    acc += partial - other;
  }
  if (is_re) out[n * 16 + t] = acc;
}

extern "C" void kernel_launch(void* const* d_in, const int* in_sizes, int n_in,
                              void* d_out, int out_size, void* d_ws, size_t ws_size,
                              hipStream_t stream) {
  const float* inputs = (const float*)d_in[0];
  const float* Pu = (const float*)d_in[1];
  const float* Pv = (const float*)d_in[2];
  const float* Pw = (const float*)d_in[3];
  float* out = (float*)d_out;

  if (ws_size >= WS_NEED) {
    char* ws = (char*)d_ws;
    __half*   T       = (__half*)ws;
    float4*   sortedC = (float4*)(ws + OFF_SORTED);
    float*    partial = (float*)(ws + OFF_PARTIAL);
    unsigned* hist    = (unsigned*)(ws + OFF_HIST);

    // transpose + fp16 convert
    {
      dim3 tb(32, 8), tg(65536 / 32, 256 / 64, 3);
      PREFFFT_trans_k<<<tg, tb, 0, stream>>>(Pu, Pv, Pw, T);
    }
    // counting sort per plane
    hipMemsetAsync(hist, 0, (size_t)3 * 65536 * 4, stream);
    PREFFFT_hist_k<<<NPTS / 256, 256, 0, stream>>>(inputs, hist);
    PREFFFT_scan_k<<<3, 1024, 0, stream>>>(hist);
    PREFFFT_scat_k<<<NPTS / 256, 256, 0, stream>>>(inputs, hist, sortedC);
    // sample (3 planes, sorted order) -> partials
    {
      dim3 tg(NPTS / 8, 3);
      PREFFFT_samp_k<<<tg, 256, 0, stream>>>(sortedC, T, partial);
    }
    // reduce partials -> out
    PREFFFT_red_k<<<(NPTS * 16 / 4) / 256, 256, 0, stream>>>((const f4*)partial,
                                                             (f4*)out);
  } else {
    PREFFFT_fallback_k<<<NPTS / 8, 256, 0, stream>>>(inputs, Pu, Pv, Pw, out);
  }
}

// Round 5
// 233.985 us; speedup vs baseline: 2.1155x; 1.1011x over previous
//
#include <hip/hip_runtime.h>
#include <hip/hip_fp16.h>
#include <math.h>

#define NPTS 262144
#define PLANE_ELEMS 16777216u   // 256*256*256

typedef __attribute__((ext_vector_type(4))) float f4;
typedef __attribute__((ext_vector_type(8))) unsigned short us8;
typedef __attribute__((ext_vector_type(4))) unsigned int u4;

// ws layout (bytes):
//   [0, 96 MB)        : fp16 transposed planes (3 x 32 MB)
//   +12.58 MB         : sortedC float4[3][NPTS] (c0,c1,c2,bits(n))
//   +25.17 MB         : partial fp16[3][NPTS][16]
//   +0.75 MB          : hist unsigned[3][65536]
#define OFF_SORTED   (3ull * PLANE_ELEMS * 2ull)
#define OFF_PARTIAL  (OFF_SORTED + (size_t)3 * NPTS * 16)
#define OFF_HIST     (OFF_PARTIAL + (size_t)3 * NPTS * 16 * 2)
#define WS_NEED      (OFF_HIST + (size_t)3 * 65536 * 4)

__device__ __forceinline__ void plane_xy(int p, float c0, float c1, float c2,
                                         float& gx, float& gy, float& ax) {
  if (p == 0)      { gx = c1; gy = c2; ax = c0; }
  else if (p == 1) { gx = c0; gy = c2; ax = c1; }
  else             { gx = c0; gy = c1; ax = c2; }
}

__device__ __forceinline__ int cell_of(float g) {
  float i = (g + 1.f) * 0.5f * 255.f;
  int x0 = (int)floorf(i);
  return x0 < 0 ? 0 : (x0 > 255 ? 255 : x0);
}

// ---------------------------------------------------------------------------
// Transpose + convert: (C, H*W) fp32 -> (H*W, C) fp16. 64c x 64hw tiles,
// float4 global reads (256B/wave-row), 16B fp16 writes (128B/row-octet).
// grid (1024, 4, 3), block 256.
// ---------------------------------------------------------------------------
__global__ __launch_bounds__(256) void PREFFFT_trans_k(
    const float* __restrict__ Pu, const float* __restrict__ Pv,
    const float* __restrict__ Pw, __half* __restrict__ dst0) {
  __shared__ float tile[64][65];
  const float* src = blockIdx.z == 0 ? Pu : (blockIdx.z == 1 ? Pv : Pw);
  __half* dst = dst0 + (size_t)blockIdx.z * PLANE_ELEMS;
  unsigned hw0 = blockIdx.x * 64u;
  unsigned c0  = blockIdx.y * 64u;
  int tid = threadIdx.x;
  int lr = tid >> 4, lc = tid & 15;
#pragma unroll
  for (int j = 0; j < 4; ++j) {
    int r = lr + j * 16;
    f4 v = *(const f4*)(src + (size_t)(c0 + r) * 65536u + hw0 + lc * 4);
    tile[r][lc * 4 + 0] = v.x; tile[r][lc * 4 + 1] = v.y;
    tile[r][lc * 4 + 2] = v.z; tile[r][lc * 4 + 3] = v.w;
  }
  __syncthreads();
  int wr = tid >> 3, ws = tid & 7;
#pragma unroll
  for (int j = 0; j < 2; ++j) {
    int row = wr + j * 32;
    __half2 h[4];
#pragma unroll
    for (int k = 0; k < 4; ++k)
      h[k] = __floats2half2_rn(tile[ws * 8 + 2 * k][row],
                               tile[ws * 8 + 2 * k + 1][row]);
    *(us8*)(dst + (size_t)(hw0 + row) * 256u + c0 + ws * 8) = *(us8*)h;
  }
}

// ---------------------------------------------------------------------------
// Counting sort: histogram / scan / scatter (16-bit plane-cell keys).
// ---------------------------------------------------------------------------
__global__ __launch_bounds__(256) void PREFFFT_hist_k(
    const float* __restrict__ inputs, unsigned* __restrict__ hist) {
  int n = blockIdx.x * 256 + threadIdx.x;
  if (n >= NPTS) return;
  float c0 = inputs[n * 3 + 0], c1 = inputs[n * 3 + 1], c2 = inputs[n * 3 + 2];
#pragma unroll
  for (int p = 0; p < 3; ++p) {
    float gx, gy, ax;
    plane_xy(p, c0, c1, c2, gx, gy, ax);
    int key = (cell_of(gy) << 8) | cell_of(gx);
    atomicAdd(&hist[p * 65536 + key], 1u);
  }
}

__global__ __launch_bounds__(1024) void PREFFFT_scan_k(unsigned* __restrict__ hist) {
  __shared__ unsigned part[1024];
  unsigned* h = hist + (size_t)blockIdx.x * 65536;
  int t = threadIdx.x;
  unsigned s = 0;
#pragma unroll 8
  for (int i = 0; i < 64; ++i) s += h[t * 64 + i];
  part[t] = s;
  __syncthreads();
  for (int off = 1; off < 1024; off <<= 1) {
    unsigned v = (t >= off) ? part[t - off] : 0u;
    __syncthreads();
    part[t] += v;
    __syncthreads();
  }
  unsigned run = (t == 0) ? 0u : part[t - 1];
#pragma unroll 8
  for (int i = 0; i < 64; ++i) {
    unsigned c = h[t * 64 + i];
    h[t * 64 + i] = run;
    run += c;
  }
}

__global__ __launch_bounds__(256) void PREFFFT_scat_k(
    const float* __restrict__ inputs, unsigned* __restrict__ hist,
    float4* __restrict__ sortedC) {
  int n = blockIdx.x * 256 + threadIdx.x;
  if (n >= NPTS) return;
  float c0 = inputs[n * 3 + 0], c1 = inputs[n * 3 + 1], c2 = inputs[n * 3 + 2];
#pragma unroll
  for (int p = 0; p < 3; ++p) {
    float gx, gy, ax;
    plane_xy(p, c0, c1, c2, gx, gy, ax);
    int key = (cell_of(gy) << 8) | cell_of(gx);
    unsigned pos = atomicAdd(&hist[p * 65536 + key], 1u);
    sortedC[(size_t)p * NPTS + pos] =
        make_float4(c0, c1, c2, __uint_as_float((unsigned)n));
  }
}

// ---------------------------------------------------------------------------
// Sample pass: 8 lanes/point. Lane t owns re-ch2 {2t,2t+1} (plane ch t*16..+15)
// and im-ch2 {16+2t,16+2t+1} (plane ch 128+t*16..+15). Bilinear in packed
// fp16 (v_pk_fma_f16); Fourier dots in f32 with shared double-angle trig.
// Writes fp16 partials (4B/lane, 32B/point, by original index n).
// grid (NPTS/32, 3), block 256.
// ---------------------------------------------------------------------------
__global__ __launch_bounds__(256) void PREFFFT_samp_k(
    const float4* __restrict__ sortedC, const __half* __restrict__ T,
    __half* __restrict__ partial) {
  int p = blockIdx.y;
  int bx = blockIdx.x;                      // 0..8191
  int lbx = (bx & 7) * 1024 + (bx >> 3);    // XCD-contiguous chunks
  int slot = lbx * 32 + ((int)threadIdx.x >> 3);
  int t = threadIdx.x & 7;

  float4 sc = sortedC[(size_t)p * NPTS + slot];
  unsigned n = __float_as_uint(sc.w);
  float gx, gy, ax;
  plane_xy(p, sc.x, sc.y, sc.z, gx, gy, ax);

  float ix = (gx + 1.f) * 0.5f * 255.f;
  float iy = (gy + 1.f) * 0.5f * 255.f;
  float x0f = floorf(ix), y0f = floorf(iy);
  float wx = ix - x0f, wy = iy - y0f;
  int x0 = (int)x0f; x0 = x0 < 0 ? 0 : (x0 > 255 ? 255 : x0);
  int y0 = (int)y0f; y0 = y0 < 0 ? 0 : (y0 > 255 ? 255 : y0);
  int x1 = x0 + 1 > 255 ? 255 : x0 + 1;
  int y1 = y0 + 1 > 255 ? 255 : y0 + 1;
  float w00 = (1.f - wx) * (1.f - wy);
  float w01 = wx * (1.f - wy);
  float w10 = (1.f - wx) * wy;
  float w11 = wx * wy;

  const __half* __restrict__ P = T + (size_t)p * PLANE_ELEMS;
  int r00 = (y0 * 256 + x0) * 256, r01 = (y0 * 256 + x1) * 256;
  int r10 = (y1 * 256 + x0) * 256, r11 = (y1 * 256 + x1) * 256;
  int ore = t * 16;         // re channels t*16..t*16+15
  int oim = 128 + t * 16;   // im channels

  // 16 x 16B loads (4 corners x {re_lo, re_hi, im_lo, im_hi})
  f4 a0 = *(const f4*)(P + r00 + ore),     a1 = *(const f4*)(P + r00 + ore + 8);
  f4 a2 = *(const f4*)(P + r00 + oim),     a3 = *(const f4*)(P + r00 + oim + 8);
  f4 b0 = *(const f4*)(P + r01 + ore),     b1 = *(const f4*)(P + r01 + ore + 8);
  f4 b2 = *(const f4*)(P + r01 + oim),     b3 = *(const f4*)(P + r01 + oim + 8);
  f4 c0v = *(const f4*)(P + r10 + ore),    c1v = *(const f4*)(P + r10 + ore + 8);
  f4 c2v = *(const f4*)(P + r10 + oim),    c3v = *(const f4*)(P + r10 + oim + 8);
  f4 d0 = *(const f4*)(P + r11 + ore),     d1 = *(const f4*)(P + r11 + ore + 8);
  f4 d2 = *(const f4*)(P + r11 + oim),     d3 = *(const f4*)(P + r11 + oim + 8);

  __half2 hw00 = __float2half2_rn(w00), hw01 = __float2half2_rn(w01);
  __half2 hw10 = __float2half2_rn(w10), hw11 = __float2half2_rn(w11);

  // bilinear blend in packed fp16: 16 h2 outputs (8 re, 8 im)
  __half2 bre[8], bim[8];
#pragma unroll
  for (int q = 0; q < 4; ++q) {
    const __half2* pa;
    pa = (const __half2*)&a0;  __half2 v;
    v = __hmul2(pa[q], hw00);
    v = __hfma2(((const __half2*)&b0)[q],  hw01, v);
    v = __hfma2(((const __half2*)&c0v)[q], hw10, v);
    bre[q] = __hfma2(((const __half2*)&d0)[q], hw11, v);

    v = __hmul2(((const __half2*)&a1)[q], hw00);
    v = __hfma2(((const __half2*)&b1)[q],  hw01, v);
    v = __hfma2(((const __half2*)&c1v)[q], hw10, v);
    bre[q + 4] = __hfma2(((const __half2*)&d1)[q], hw11, v);

    v = __hmul2(((const __half2*)&a2)[q], hw00);
    v = __hfma2(((const __half2*)&b2)[q],  hw01, v);
    v = __hfma2(((const __half2*)&c2v)[q], hw10, v);
    bim[q] = __hfma2(((const __half2*)&d2)[q], hw11, v);

    v = __hmul2(((const __half2*)&a3)[q], hw00);
    v = __hfma2(((const __half2*)&b3)[q],  hw01, v);
    v = __hfma2(((const __half2*)&c3v)[q], hw10, v);
    bim[q + 4] = __hfma2(((const __half2*)&d3)[q], hw11, v);
  }

  // unpack to f32: fre[0..7] = ch2=2t r=0..7; fre[8..15] = ch2=2t+1
  float fre[16], fim[16];
#pragma unroll
  for (int q = 0; q < 8; ++q) {
    float2 vr = __half22float2(bre[q]);
    float2 vi = __half22float2(bim[q]);
    fre[2 * q] = vr.x; fre[2 * q + 1] = vr.y;
    fim[2 * q] = vi.x; fim[2 * q + 1] = vi.y;
  }

  // Fourier: theta_r = theta1 * 2^(r-1); r=0 term cos=1 / sin=0.
  float cs = (ax + 1.f) * 0.5f * 255.f;
  float th = 6.283185307179586f * cs * (1.f / 256.f);
  float s, c;
  __sincosf(th, &s, &c);
  float aR0 = fre[0], aR1 = fre[8];
  float aI0 = 0.f,    aI1 = 0.f;
#pragma unroll
  for (int r = 1; r < 8; ++r) {
    aR0 += fre[r] * c;     aR1 += fre[8 + r] * c;
    aI0 += fim[r] * s;     aI1 += fim[8 + r] * s;
    if (r < 7) {
      float c2 = c + c;
      float cn = c2 * c - 1.f;   // cos(2a) = 2cos^2 - 1
      s = c2 * s;                // sin(2a) = 2 sin cos
      c = cn;
    }
  }

  *(__half2*)(partial + ((size_t)p * NPTS + n) * 16 + 2 * t) =
      __floats2half2_rn(aR0 - aI0, aR1 - aI1);
}

// ---------------------------------------------------------------------------
// Reduce: out = sum of 3 fp16 partials, f32 output. 8 outputs/thread.
// ---------------------------------------------------------------------------
__global__ __launch_bounds__(256) void PREFFFT_red_k(
    const __half* __restrict__ part, float* __restrict__ out) {
  size_t i = (size_t)blockIdx.x * 256 + threadIdx.x;  // < 524288
  const size_t PS = (size_t)NPTS * 16;
  union H8 { u4 v; __half2 h[4]; };
  H8 a, b, c;
  a.v = *(const u4*)(part + i * 8);
  b.v = *(const u4*)(part + PS + i * 8);
  c.v = *(const u4*)(part + 2 * PS + i * 8);
  f4 o0, o1;
#pragma unroll
  for (int k = 0; k < 4; ++k) {
    float2 fa = __half22float2(a.h[k]);
    float2 fb = __half22float2(b.h[k]);
    float2 fc = __half22float2(c.h[k]);
    float lo = fa.x + fb.x + fc.x;
    float hi = fa.y + fb.y + fc.y;
    if (k < 2) { o0[2 * k] = lo; o0[2 * k + 1] = hi; }
    else       { o1[2 * (k - 2)] = lo; o1[2 * (k - 2) + 1] = hi; }
  }
  ((f4*)out)[i * 2] = o0;
  ((f4*)out)[i * 2 + 1] = o1;
}

// ---------------------------------------------------------------------------
// Fallback (ws too small): original (C,H,W) fp32 direct, slow but correct.
// ---------------------------------------------------------------------------
__global__ __launch_bounds__(256) void PREFFFT_fallback_k(
    const float* __restrict__ inputs, const float* __restrict__ Tu,
    const float* __restrict__ Tv, const float* __restrict__ Tw,
    float* __restrict__ out) {
  int gtid = blockIdx.x * 256 + threadIdx.x;
  int n = gtid >> 5;
  int t = threadIdx.x & 31;
  const bool is_re = t < 16;
  float c0 = inputs[n * 3 + 0], c1 = inputs[n * 3 + 1], c2 = inputs[n * 3 + 2];
  const float* PL[3] = {Tu, Tv, Tw};
  float acc = 0.f;
#pragma unroll
  for (int p = 0; p < 3; ++p) {
    float gx, gy, ax;
    plane_xy(p, c0, c1, c2, gx, gy, ax);
    float ix = (gx + 1.f) * 0.5f * 255.f;
    float iy = (gy + 1.f) * 0.5f * 255.f;
    float x0f = floorf(ix), y0f = floorf(iy);
    float wx = ix - x0f, wy = iy - y0f;
    int x0 = (int)x0f; x0 = x0 < 0 ? 0 : (x0 > 255 ? 255 : x0);
    int y0 = (int)y0f; y0 = y0 < 0 ? 0 : (y0 > 255 ? 255 : y0);
    int x1 = x0 + 1 > 255 ? 255 : x0 + 1;
    int y1 = y0 + 1 > 255 ? 255 : y0 + 1;
    float w00 = (1.f - wx) * (1.f - wy), w01 = wx * (1.f - wy);
    float w10 = (1.f - wx) * wy, w11 = wx * wy;
    int i00 = y0 * 256 + x0, i01 = y0 * 256 + x1;
    int i10 = y1 * 256 + x0, i11 = y1 * 256 + x1;
    float b[8];
#pragma unroll
    for (int j = 0; j < 8; ++j) {
      const float* base = PL[p] + (size_t)(t * 8 + j) * 65536u;
      b[j] = w00 * base[i00] + w01 * base[i01] + w10 * base[i10] + w11 * base[i11];
    }
    float csv = (ax + 1.f) * 0.5f * 255.f;
    float theta1 = 6.283185307179586f * csv * (1.f / 256.f);
    float partial = is_re ? b[0] : 0.f;
#pragma unroll
    for (int r = 1; r < 8; ++r) {
      float thr = theta1 * (float)(1 << (r - 1));
      float s, c;
      __sincosf(thr, &s, &c);
      partial += b[r] * (is_re ? c : s);
    }
    float other = __shfl_xor(partial, 16);
    acc += partial - other;
  }
  if (is_re) out[n * 16 + t] = acc;
}

extern "C" void kernel_launch(void* const* d_in, const int* in_sizes, int n_in,
                              void* d_out, int out_size, void* d_ws, size_t ws_size,
                              hipStream_t stream) {
  const float* inputs = (const float*)d_in[0];
  const float* Pu = (const float*)d_in[1];
  const float* Pv = (const float*)d_in[2];
  const float* Pw = (const float*)d_in[3];
  float* out = (float*)d_out;

  if (ws_size >= WS_NEED) {
    char* ws = (char*)d_ws;
    __half*   T       = (__half*)ws;
    float4*   sortedC = (float4*)(ws + OFF_SORTED);
    __half*   partial = (__half*)(ws + OFF_PARTIAL);
    unsigned* hist    = (unsigned*)(ws + OFF_HIST);

    {
      dim3 tg(1024, 4, 3);
      PREFFFT_trans_k<<<tg, 256, 0, stream>>>(Pu, Pv, Pw, T);
    }
    hipMemsetAsync(hist, 0, (size_t)3 * 65536 * 4, stream);
    PREFFFT_hist_k<<<NPTS / 256, 256, 0, stream>>>(inputs, hist);
    PREFFFT_scan_k<<<3, 1024, 0, stream>>>(hist);
    PREFFFT_scat_k<<<NPTS / 256, 256, 0, stream>>>(inputs, hist, sortedC);
    {
      dim3 tg(NPTS / 32, 3);
      PREFFFT_samp_k<<<tg, 256, 0, stream>>>(sortedC, T, partial);
    }
    PREFFFT_red_k<<<2048, 256, 0, stream>>>(partial, out);
  } else {
    PREFFFT_fallback_k<<<NPTS / 8, 256, 0, stream>>>(inputs, Pu, Pv, Pw, out);
  }
}

// Round 6
// 232.905 us; speedup vs baseline: 2.1253x; 1.0046x over previous
//
#include <hip/hip_runtime.h>
#include <hip/hip_fp16.h>
#include <math.h>

#define NPTS 262144
#define PLANE_ELEMS 16777216u   // 256*256*256

typedef __attribute__((ext_vector_type(4))) float f4;
typedef __attribute__((ext_vector_type(8))) unsigned short us8;
typedef __attribute__((ext_vector_type(4))) unsigned int u4;

// ws layout (bytes):
//   [0, 96 MB)        : fp16 transposed planes (3 x 32 MB)
//   +12.58 MB         : sortedC float4[3][NPTS] (c0,c1,c2,bits(n))
//   +25.17 MB         : partial fp16[3][NPTS][16]
//   +0.75 MB          : hist unsigned[3][65536]
#define OFF_SORTED   (3ull * PLANE_ELEMS * 2ull)
#define OFF_PARTIAL  (OFF_SORTED + (size_t)3 * NPTS * 16)
#define OFF_HIST     (OFF_PARTIAL + (size_t)3 * NPTS * 16 * 2)
#define WS_NEED      (OFF_HIST + (size_t)3 * 65536 * 4)

__device__ __forceinline__ void plane_xy(int p, float c0, float c1, float c2,
                                         float& gx, float& gy, float& ax) {
  if (p == 0)      { gx = c1; gy = c2; ax = c0; }
  else if (p == 1) { gx = c0; gy = c2; ax = c1; }
  else             { gx = c0; gy = c1; ax = c2; }
}

__device__ __forceinline__ int cell_of(float g) {
  float i = (g + 1.f) * 0.5f * 255.f;
  int x0 = (int)floorf(i);
  return x0 < 0 ? 0 : (x0 > 255 ? 255 : x0);
}

// ---------------------------------------------------------------------------
// Transpose + convert: (C, H*W) fp32 -> (H*W, C) fp16.
// Tile: 64 c x 256 hw per block. grid (256, 4, 3), block 256.
// Read: 16 independent float4 loads/thread (1KB contiguous per row-read).
// LDS: half2 (c,c+1) words, [hw][rp ^ (hw>>3)] swizzle, pad 36 u32/row.
// Write: 8x ds_read_b128 + uniform XOR unpermute + 8x 16B stores.
// ---------------------------------------------------------------------------
__global__ __launch_bounds__(256) void PREFFFT_trans_k(
    const float* __restrict__ Pu, const float* __restrict__ Pv,
    const float* __restrict__ Pw, __half* __restrict__ dst0) {
  __shared__ unsigned tile[256 * 36];  // 36 KB
  const float* src = blockIdx.z == 0 ? Pu : (blockIdx.z == 1 ? Pv : Pw);
  __half* dst = dst0 + (size_t)blockIdx.z * PLANE_ELEMS;
  const unsigned hw0 = blockIdx.x * 256u;
  const unsigned c0 = blockIdx.y * 64u;
  const int tid = threadIdx.x;

  // ---- read phase: 16 float4 loads, all independent, issued up front ----
  f4 va[8], vb[8];
#pragma unroll
  for (int j = 0; j < 8; ++j) {
    int idx = j * 256 + tid;
    int rp = idx >> 6;        // 0..31 : c-pair index (c = c0 + 2rp, +1)
    int q = idx & 63;         // 0..63 : f4 column (hw = 4q..4q+3)
    const float* base = src + (size_t)(c0 + 2 * rp) * 65536u + hw0 + 4 * q;
    va[j] = *(const f4*)(base);
    vb[j] = *(const f4*)(base + 65536);
  }
  // ---- convert + swizzled LDS write (conflict-free) ----
#pragma unroll
  for (int j = 0; j < 8; ++j) {
    int idx = j * 256 + tid;
    int rp = idx >> 6;
    int q = idx & 63;
#pragma unroll
    for (int k = 0; k < 4; ++k) {
      int hw = 4 * q + k;
      __half2 h = __floats2half2_rn(va[j][k], vb[j][k]);
      tile[hw * 36 + (rp ^ (hw >> 3))] = *(unsigned*)&h;
    }
  }
  __syncthreads();
  // ---- write phase: b128 LDS reads + 16B global stores ----
  int seg = tid & 7;          // 0..7 : 16B segment within the 128B c-slice
#pragma unroll
  for (int jj = 0; jj < 8; ++jj) {
    int hw = jj * 32 + (tid >> 3);
    int s = hw >> 3;          // wave-uniform
    u4 v = *(const u4*)(tile + hw * 36 + 4 * ((seg ^ (s >> 2)) & 7));
    u4 o;
    switch (s & 3) {          // wave-uniform switch: unpermute low2 of rp
      case 0: o = v; break;
      case 1: o = u4{v.y, v.x, v.w, v.z}; break;
      case 2: o = u4{v.z, v.w, v.x, v.y}; break;
      default: o = u4{v.w, v.z, v.y, v.x}; break;
    }
    *(u4*)((char*)dst + ((size_t)(hw0 + hw) * 256u + c0) * 2u + seg * 16u) = o;
  }
}

// ---------------------------------------------------------------------------
// Counting sort: histogram / scan / scatter (16-bit plane-cell keys).
// ---------------------------------------------------------------------------
__global__ __launch_bounds__(256) void PREFFFT_hist_k(
    const float* __restrict__ inputs, unsigned* __restrict__ hist) {
  int n = blockIdx.x * 256 + threadIdx.x;
  if (n >= NPTS) return;
  float c0 = inputs[n * 3 + 0], c1 = inputs[n * 3 + 1], c2 = inputs[n * 3 + 2];
#pragma unroll
  for (int p = 0; p < 3; ++p) {
    float gx, gy, ax;
    plane_xy(p, c0, c1, c2, gx, gy, ax);
    int key = (cell_of(gy) << 8) | cell_of(gx);
    atomicAdd(&hist[p * 65536 + key], 1u);
  }
}

__global__ __launch_bounds__(1024) void PREFFFT_scan_k(unsigned* __restrict__ hist) {
  __shared__ unsigned part[1024];
  unsigned* h = hist + (size_t)blockIdx.x * 65536;
  int t = threadIdx.x;
  unsigned s = 0;
#pragma unroll 8
  for (int i = 0; i < 64; ++i) s += h[t * 64 + i];
  part[t] = s;
  __syncthreads();
  for (int off = 1; off < 1024; off <<= 1) {
    unsigned v = (t >= off) ? part[t - off] : 0u;
    __syncthreads();
    part[t] += v;
    __syncthreads();
  }
  unsigned run = (t == 0) ? 0u : part[t - 1];
#pragma unroll 8
  for (int i = 0; i < 64; ++i) {
    unsigned c = h[t * 64 + i];
    h[t * 64 + i] = run;
    run += c;
  }
}

__global__ __launch_bounds__(256) void PREFFFT_scat_k(
    const float* __restrict__ inputs, unsigned* __restrict__ hist,
    float4* __restrict__ sortedC) {
  int n = blockIdx.x * 256 + threadIdx.x;
  if (n >= NPTS) return;
  float c0 = inputs[n * 3 + 0], c1 = inputs[n * 3 + 1], c2 = inputs[n * 3 + 2];
#pragma unroll
  for (int p = 0; p < 3; ++p) {
    float gx, gy, ax;
    plane_xy(p, c0, c1, c2, gx, gy, ax);
    int key = (cell_of(gy) << 8) | cell_of(gx);
    unsigned pos = atomicAdd(&hist[p * 65536 + key], 1u);
    sortedC[(size_t)p * NPTS + pos] =
        make_float4(c0, c1, c2, __uint_as_float((unsigned)n));
  }
}

// ---------------------------------------------------------------------------
// Sample pass: 8 lanes/point. Lane t owns re-ch2 {2t,2t+1} (plane ch t*16..+15)
// and im-ch2 {16+2t,16+2t+1} (plane ch 128+t*16..+15). Bilinear in packed
// fp16 (v_pk_fma_f16); Fourier dots in f32 with shared double-angle trig.
// Writes fp16 partials (4B/lane, 32B/point, by original index n).
// grid (NPTS/32, 3), block 256.
// ---------------------------------------------------------------------------
__global__ __launch_bounds__(256) void PREFFFT_samp_k(
    const float4* __restrict__ sortedC, const __half* __restrict__ T,
    __half* __restrict__ partial) {
  int p = blockIdx.y;
  int bx = blockIdx.x;                      // 0..8191
  int lbx = (bx & 7) * 1024 + (bx >> 3);    // XCD-contiguous chunks
  int slot = lbx * 32 + ((int)threadIdx.x >> 3);
  int t = threadIdx.x & 7;

  float4 sc = sortedC[(size_t)p * NPTS + slot];
  unsigned n = __float_as_uint(sc.w);
  float gx, gy, ax;
  plane_xy(p, sc.x, sc.y, sc.z, gx, gy, ax);

  float ix = (gx + 1.f) * 0.5f * 255.f;
  float iy = (gy + 1.f) * 0.5f * 255.f;
  float x0f = floorf(ix), y0f = floorf(iy);
  float wx = ix - x0f, wy = iy - y0f;
  int x0 = (int)x0f; x0 = x0 < 0 ? 0 : (x0 > 255 ? 255 : x0);
  int y0 = (int)y0f; y0 = y0 < 0 ? 0 : (y0 > 255 ? 255 : y0);
  int x1 = x0 + 1 > 255 ? 255 : x0 + 1;
  int y1 = y0 + 1 > 255 ? 255 : y0 + 1;
  float w00 = (1.f - wx) * (1.f - wy);
  float w01 = wx * (1.f - wy);
  float w10 = (1.f - wx) * wy;
  float w11 = wx * wy;

  const __half* __restrict__ P = T + (size_t)p * PLANE_ELEMS;
  int r00 = (y0 * 256 + x0) * 256, r01 = (y0 * 256 + x1) * 256;
  int r10 = (y1 * 256 + x0) * 256, r11 = (y1 * 256 + x1) * 256;
  int ore = t * 16;         // re channels t*16..t*16+15
  int oim = 128 + t * 16;   // im channels

  // 16 x 16B loads (4 corners x {re_lo, re_hi, im_lo, im_hi})
  f4 a0 = *(const f4*)(P + r00 + ore),     a1 = *(const f4*)(P + r00 + ore + 8);
  f4 a2 = *(const f4*)(P + r00 + oim),     a3 = *(const f4*)(P + r00 + oim + 8);
  f4 b0 = *(const f4*)(P + r01 + ore),     b1 = *(const f4*)(P + r01 + ore + 8);
  f4 b2 = *(const f4*)(P + r01 + oim),     b3 = *(const f4*)(P + r01 + oim + 8);
  f4 c0v = *(const f4*)(P + r10 + ore),    c1v = *(const f4*)(P + r10 + ore + 8);
  f4 c2v = *(const f4*)(P + r10 + oim),    c3v = *(const f4*)(P + r10 + oim + 8);
  f4 d0 = *(const f4*)(P + r11 + ore),     d1 = *(const f4*)(P + r11 + ore + 8);
  f4 d2 = *(const f4*)(P + r11 + oim),     d3 = *(const f4*)(P + r11 + oim + 8);

  __half2 hw00 = __float2half2_rn(w00), hw01 = __float2half2_rn(w01);
  __half2 hw10 = __float2half2_rn(w10), hw11 = __float2half2_rn(w11);

  // bilinear blend in packed fp16: 16 h2 outputs (8 re, 8 im)
  __half2 bre[8], bim[8];
#pragma unroll
  for (int q = 0; q < 4; ++q) {
    __half2 v;
    v = __hmul2(((const __half2*)&a0)[q], hw00);
    v = __hfma2(((const __half2*)&b0)[q],  hw01, v);
    v = __hfma2(((const __half2*)&c0v)[q], hw10, v);
    bre[q] = __hfma2(((const __half2*)&d0)[q], hw11, v);

    v = __hmul2(((const __half2*)&a1)[q], hw00);
    v = __hfma2(((const __half2*)&b1)[q],  hw01, v);
    v = __hfma2(((const __half2*)&c1v)[q], hw10, v);
    bre[q + 4] = __hfma2(((const __half2*)&d1)[q], hw11, v);

    v = __hmul2(((const __half2*)&a2)[q], hw00);
    v = __hfma2(((const __half2*)&b2)[q],  hw01, v);
    v = __hfma2(((const __half2*)&c2v)[q], hw10, v);
    bim[q] = __hfma2(((const __half2*)&d2)[q], hw11, v);

    v = __hmul2(((const __half2*)&a3)[q], hw00);
    v = __hfma2(((const __half2*)&b3)[q],  hw01, v);
    v = __hfma2(((const __half2*)&c3v)[q], hw10, v);
    bim[q + 4] = __hfma2(((const __half2*)&d3)[q], hw11, v);
  }

  // unpack to f32: fre[0..7] = ch2=2t r=0..7; fre[8..15] = ch2=2t+1
  float fre[16], fim[16];
#pragma unroll
  for (int q = 0; q < 8; ++q) {
    float2 vr = __half22float2(bre[q]);
    float2 vi = __half22float2(bim[q]);
    fre[2 * q] = vr.x; fre[2 * q + 1] = vr.y;
    fim[2 * q] = vi.x; fim[2 * q + 1] = vi.y;
  }

  // Fourier: theta_r = theta1 * 2^(r-1); r=0 term cos=1 / sin=0.
  float cs = (ax + 1.f) * 0.5f * 255.f;
  float th = 6.283185307179586f * cs * (1.f / 256.f);
  float s, c;
  __sincosf(th, &s, &c);
  float aR0 = fre[0], aR1 = fre[8];
  float aI0 = 0.f,    aI1 = 0.f;
#pragma unroll
  for (int r = 1; r < 8; ++r) {
    aR0 += fre[r] * c;     aR1 += fre[8 + r] * c;
    aI0 += fim[r] * s;     aI1 += fim[8 + r] * s;
    if (r < 7) {
      float c2 = c + c;
      float cn = c2 * c - 1.f;   // cos(2a) = 2cos^2 - 1
      s = c2 * s;                // sin(2a) = 2 sin cos
      c = cn;
    }
  }

  *(__half2*)(partial + ((size_t)p * NPTS + n) * 16 + 2 * t) =
      __floats2half2_rn(aR0 - aI0, aR1 - aI1);
}

// ---------------------------------------------------------------------------
// Reduce: out = sum of 3 fp16 partials, f32 output. 8 outputs/thread.
// ---------------------------------------------------------------------------
__global__ __launch_bounds__(256) void PREFFFT_red_k(
    const __half* __restrict__ part, float* __restrict__ out) {
  size_t i = (size_t)blockIdx.x * 256 + threadIdx.x;  // < 524288
  const size_t PS = (size_t)NPTS * 16;
  union H8 { u4 v; __half2 h[4]; };
  H8 a, b, c;
  a.v = *(const u4*)(part + i * 8);
  b.v = *(const u4*)(part + PS + i * 8);
  c.v = *(const u4*)(part + 2 * PS + i * 8);
  f4 o0, o1;
#pragma unroll
  for (int k = 0; k < 4; ++k) {
    float2 fa = __half22float2(a.h[k]);
    float2 fb = __half22float2(b.h[k]);
    float2 fc = __half22float2(c.h[k]);
    float lo = fa.x + fb.x + fc.x;
    float hi = fa.y + fb.y + fc.y;
    if (k < 2) { o0[2 * k] = lo; o0[2 * k + 1] = hi; }
    else       { o1[2 * (k - 2)] = lo; o1[2 * (k - 2) + 1] = hi; }
  }
  ((f4*)out)[i * 2] = o0;
  ((f4*)out)[i * 2 + 1] = o1;
}

// ---------------------------------------------------------------------------
// Fallback (ws too small): original (C,H,W) fp32 direct, slow but correct.
// ---------------------------------------------------------------------------
__global__ __launch_bounds__(256) void PREFFFT_fallback_k(
    const float* __restrict__ inputs, const float* __restrict__ Tu,
    const float* __restrict__ Tv, const float* __restrict__ Tw,
    float* __restrict__ out) {
  int gtid = blockIdx.x * 256 + threadIdx.x;
  int n = gtid >> 5;
  int t = threadIdx.x & 31;
  const bool is_re = t < 16;
  float c0 = inputs[n * 3 + 0], c1 = inputs[n * 3 + 1], c2 = inputs[n * 3 + 2];
  const float* PL[3] = {Tu, Tv, Tw};
  float acc = 0.f;
#pragma unroll
  for (int p = 0; p < 3; ++p) {
    float gx, gy, ax;
    plane_xy(p, c0, c1, c2, gx, gy, ax);
    float ix = (gx + 1.f) * 0.5f * 255.f;
    float iy = (gy + 1.f) * 0.5f * 255.f;
    float x0f = floorf(ix), y0f = floorf(iy);
    float wx = ix - x0f, wy = iy - y0f;
    int x0 = (int)x0f; x0 = x0 < 0 ? 0 : (x0 > 255 ? 255 : x0);
    int y0 = (int)y0f; y0 = y0 < 0 ? 0 : (y0 > 255 ? 255 : y0);
    int x1 = x0 + 1 > 255 ? 255 : x0 + 1;
    int y1 = y0 + 1 > 255 ? 255 : y0 + 1;
    float w00 = (1.f - wx) * (1.f - wy), w01 = wx * (1.f - wy);
    float w10 = (1.f - wx) * wy, w11 = wx * wy;
    int i00 = y0 * 256 + x0, i01 = y0 * 256 + x1;
    int i10 = y1 * 256 + x0, i11 = y1 * 256 + x1;
    float b[8];
#pragma unroll
    for (int j = 0; j < 8; ++j) {
      const float* base = PL[p] + (size_t)(t * 8 + j) * 65536u;
      b[j] = w00 * base[i00] + w01 * base[i01] + w10 * base[i10] + w11 * base[i11];
    }
    float csv = (ax + 1.f) * 0.5f * 255.f;
    float theta1 = 6.283185307179586f * csv * (1.f / 256.f);
    float partial = is_re ? b[0] : 0.f;
#pragma unroll
    for (int r = 1; r < 8; ++r) {
      float thr = theta1 * (float)(1 << (r - 1));
      float s, c;
      __sincosf(thr, &s, &c);
      partial += b[r] * (is_re ? c : s);
    }
    float other = __shfl_xor(partial, 16);
    acc += partial - other;
  }
  if (is_re) out[n * 16 + t] = acc;
}

extern "C" void kernel_launch(void* const* d_in, const int* in_sizes, int n_in,
                              void* d_out, int out_size, void* d_ws, size_t ws_size,
                              hipStream_t stream) {
  const float* inputs = (const float*)d_in[0];
  const float* Pu = (const float*)d_in[1];
  const float* Pv = (const float*)d_in[2];
  const float* Pw = (const float*)d_in[3];
  float* out = (float*)d_out;

  if (ws_size >= WS_NEED) {
    char* ws = (char*)d_ws;
    __half*   T       = (__half*)ws;
    float4*   sortedC = (float4*)(ws + OFF_SORTED);
    __half*   partial = (__half*)(ws + OFF_PARTIAL);
    unsigned* hist    = (unsigned*)(ws + OFF_HIST);

    {
      dim3 tg(256, 4, 3);
      PREFFFT_trans_k<<<tg, 256, 0, stream>>>(Pu, Pv, Pw, T);
    }
    hipMemsetAsync(hist, 0, (size_t)3 * 65536 * 4, stream);
    PREFFFT_hist_k<<<NPTS / 256, 256, 0, stream>>>(inputs, hist);
    PREFFFT_scan_k<<<3, 1024, 0, stream>>>(hist);
    PREFFFT_scat_k<<<NPTS / 256, 256, 0, stream>>>(inputs, hist, sortedC);
    {
      dim3 tg(NPTS / 32, 3);
      PREFFFT_samp_k<<<tg, 256, 0, stream>>>(sortedC, T, partial);
    }
    PREFFFT_red_k<<<2048, 256, 0, stream>>>(partial, out);
  } else {
    PREFFFT_fallback_k<<<NPTS / 8, 256, 0, stream>>>(inputs, Pu, Pv, Pw, out);
  }
}